// Round 1
// 471.516 us; speedup vs baseline: 1.0047x; 1.0047x over previous
//
#include <hip/hip_runtime.h>
#include <hip/hip_bf16.h>

// GCN layer on MI355X.
//   pass 1 (gcn_prep): 32 rows/block: rowsum(adj)+1 -> dinv;
//                      yT[f][j] = bf16(dinv_j * x[j][f]) written as coalesced
//                      [128][32] tiles (full 64B lines, one owner block each);
//                      tail blocks: Wb = bf16(W)
//   pass 2 (gcn_main): h0 = adj @ y  (bf16 MFMA, adj converted on the fly),
//                      8 waves/block (2 waves/SIMD for latency hiding)
//                      t  = dinv_i*h0 + dinv_i^2*x   (self-loop term)
//                      z  = t @ W^T + b ; out = z / max(||z||_2, eps)
//
// ws layout: [0,2MB) yT (128x8192 bf16) | [2MB,+32KB) dinv f32 | +32KB Wb bf16

typedef __attribute__((ext_vector_type(8))) short short8;     // 8 x bf16 (4 VGPR)
typedef __attribute__((ext_vector_type(4))) float f32x4;      // MFMA acc
typedef __attribute__((ext_vector_type(4))) unsigned short us4;

static __device__ __forceinline__ unsigned short f2bf(float f) {
    // round-to-nearest-even bf16
    unsigned int u = __float_as_uint(f);
    u += 0x7FFFu + ((u >> 16) & 1u);
    return (unsigned short)(u >> 16);
}

// ---------------------------------------------------------------- pass 1 ----
// grid: 256 row-blocks (32 rows each) + 32 tail blocks (W -> bf16), 512 thr
__global__ __launch_bounds__(512) void gcn_prep(
    const float* __restrict__ adj, const float* __restrict__ x,
    const float* __restrict__ W,
    unsigned short* __restrict__ yT, float* __restrict__ dinv,
    unsigned short* __restrict__ Wb)
{
    const int tid = threadIdx.x;
    const int blk = blockIdx.x;
    if (blk >= 256) {                       // tail: convert W -> bf16
        int idx = (blk - 256) * 512 + tid;  // 32 blocks * 512 = 16384 = 128*128
        Wb[idx] = f2bf(W[idx]);
        return;
    }
    const int wave = tid >> 6;
    const int lane = tid & 63;
    const long j0 = (long)blk * 32;

    __shared__ float s_di[32];

    // rowsums: wave w owns rows j0 + 4w .. j0 + 4w+3 (8 waves x 4 rows = 32)
    for (int r = 0; r < 4; ++r) {
        const long j = j0 + wave * 4 + r;
        const float4* row = (const float4*)(adj + j * 8192L);
        float s = 0.f;
#pragma unroll
        for (int it = 0; it < 32; ++it) {   // 64 lanes * 32 it * 4 = 8192 floats
            float4 v = row[it * 64 + lane];
            s += (v.x + v.y) + (v.z + v.w);
        }
        for (int off = 1; off < 64; off <<= 1) s += __shfl_xor(s, off, 64);
        if (lane == 0) s_di[wave * 4 + r] = rsqrtf(s + 1.0f);  // +1: self loop
    }
    __syncthreads();
    if (tid < 32) dinv[j0 + tid] = s_di[tid];

    // transposed write, fully coalesced: 32 consecutive threads write one
    // 64B line yT[f][j0..j0+31]. thread t -> jj = t&31, f = p*16 + (t>>5)
    const int jj = tid & 31;
    const int fb = tid >> 5;                // 0..15
    const float di = s_di[jj];
#pragma unroll
    for (int p = 0; p < 8; ++p) {
        int f = p * 16 + fb;
        yT[(long)f * 8192 + j0 + jj] = f2bf(di * x[(j0 + jj) * 128 + f]);
    }
}

// ---------------------------------------------------------------- pass 2 ----
#define M_TILE 32
#define BKC    512           // K per chunk
#define NCHUNK 16            // 8192 / 512

// 512 threads = 8 waves (2 waves/SIMD). Wave w owns output cols w*16..w*16+15.
__global__ __launch_bounds__(512, 1) void gcn_main(
    const float* __restrict__ adj, const float* __restrict__ x,
    const float* __restrict__ bias,
    const unsigned short* __restrict__ yT, const float* __restrict__ dinv,
    const unsigned short* __restrict__ Wb, float* __restrict__ out)
{
    __shared__ unsigned short Ab[2][M_TILE][BKC];   // 2 x 32KB = 64KB

    const int tid  = threadIdx.x;
    const int wave = tid >> 6;        // 0..7
    const int lane = tid & 63;
    const int q    = lane >> 4;       // quad 0..3
    const int ln   = lane & 15;
    const int nb   = wave * 16;       // this wave's 16-col N slice
    const long rowBase = (long)blockIdx.x * M_TILE;

    f32x4 acc[2] = {};                // [mi] : (32 rows) x (16 cols)
    float4 st[8];                     // staged fp32 adj (8KB/wave per chunk)

    // stage-load: issue 8 x dwordx4 for chunk c (fire and forget)
    auto load_chunk = [&](int c) {
#pragma unroll
        for (int i = 0; i < 8; ++i) {
            int t   = wave * 8 + i;           // 0..63 insts over block
            int row = t >> 1;                 // 2 insts per 512-float row
            int col = ((t & 1) << 8) + (lane << 2);
            st[i] = *(const float4*)&adj[(rowBase + row) * 8192L + (long)c * BKC + col];
        }
    };
    // convert + write staged chunk into LDS buffer
    auto write_chunk = [&](int buf) {
#pragma unroll
        for (int i = 0; i < 8; ++i) {
            int t   = wave * 8 + i;
            int row = t >> 1;
            int col = ((t & 1) << 8) + (lane << 2);
            us4 w4;
            w4.x = f2bf(st[i].x); w4.y = f2bf(st[i].y);
            w4.z = f2bf(st[i].z); w4.w = f2bf(st[i].w);
            *(us4*)&Ab[buf][row][col] = w4;
        }
    };

    load_chunk(0);
    write_chunk(0);
    __syncthreads();

#pragma unroll 1
    for (int c = 0; c < NCHUNK; ++c) {
        const int cur = c & 1;
        if (c + 1 < NCHUNK) load_chunk(c + 1);      // in flight during compute
#pragma unroll 4
        for (int s = 0; s < BKC / 32; ++s) {        // 16 K-steps of 32
            const int k0 = s * 32 + q * 8;
            short8 a0 = *(const short8*)&Ab[cur][ln][k0];
            short8 a1 = *(const short8*)&Ab[cur][16 + ln][k0];
            const long kg = (long)c * BKC + k0;
            short8 b0 = *(const short8*)&yT[(nb + ln) * 8192L + kg];
            acc[0] = __builtin_amdgcn_mfma_f32_16x16x32_bf16(a0, b0, acc[0], 0, 0, 0);
            acc[1] = __builtin_amdgcn_mfma_f32_16x16x32_bf16(a1, b0, acc[1], 0, 0, 0);
        }
        if (c + 1 < NCHUNK) write_chunk(cur ^ 1);   // waitcnt lands here, after compute
        __syncthreads();
    }

    // ---- fused epilogue (scratch overlays Ab[0]; last compute read Ab[1]) ----
    unsigned short* t_lds = &Ab[0][0][0];           // [32][136] bf16 (pad 8)
    float* s_dinv = (float*)(t_lds + 32 * 136);
    float* s_part = s_dinv + 32;                    // [32][8] per-wave |z|^2
    float* s_inv  = s_part + 256;                   // [32]

    if (tid < 32) s_dinv[tid] = dinv[rowBase + tid];
    __syncthreads();

    // t = dinv_i * (adj@y)_i + dinv_i^2 * x_i  -> LDS (bf16)
#pragma unroll
    for (int mi = 0; mi < 2; ++mi)
#pragma unroll
        for (int r = 0; r < 4; ++r) {
            int m = mi * 16 + q * 4 + r;
            int n = nb + ln;
            float di = s_dinv[m];
            float tv = di * acc[mi][r] + di * di * x[(rowBase + m) * 128 + n];
            t_lds[m * 136 + n] = f2bf(tv);
        }
    __syncthreads();

    // z = t @ W^T via MFMA (B = Wb rows are contiguous in k)
    f32x4 z[2] = {};
#pragma unroll
    for (int s = 0; s < 4; ++s) {
        const int k0 = s * 32 + q * 8;
        short8 a0 = *(const short8*)&t_lds[ln * 136 + k0];
        short8 a1 = *(const short8*)&t_lds[(16 + ln) * 136 + k0];
        short8 b0 = *(const short8*)&Wb[(nb + ln) * 128 + k0];
        z[0] = __builtin_amdgcn_mfma_f32_16x16x32_bf16(a0, b0, z[0], 0, 0, 0);
        z[1] = __builtin_amdgcn_mfma_f32_16x16x32_bf16(a1, b0, z[1], 0, 0, 0);
    }

    // + bias, accumulate |z|^2 per row (this wave's 16 cols)
    float bv0 = bias[nb + ln];
    float zv[2][4];
    float rp[2][4];
#pragma unroll
    for (int mi = 0; mi < 2; ++mi)
#pragma unroll
        for (int r = 0; r < 4; ++r) {
            float v0 = z[mi][r] + bv0;
            zv[mi][r] = v0;
            rp[mi][r] = v0 * v0;
        }
#pragma unroll
    for (int mi = 0; mi < 2; ++mi)
#pragma unroll
        for (int r = 0; r < 4; ++r)
            for (int off = 1; off < 16; off <<= 1)
                rp[mi][r] += __shfl_xor(rp[mi][r], off, 64);   // reduce over 16 n-lanes
    if (ln == 0) {
#pragma unroll
        for (int mi = 0; mi < 2; ++mi)
#pragma unroll
            for (int r = 0; r < 4; ++r)
                s_part[(mi * 16 + q * 4 + r) * 8 + wave] = rp[mi][r];
    }
    __syncthreads();
    if (tid < 32) {
        float s = 0.f;
#pragma unroll
        for (int w = 0; w < 8; ++w) s += s_part[tid * 8 + w];
        float nrm = sqrtf(s);
        s_inv[tid] = 1.0f / fmaxf(nrm, 1e-12f);   // F.normalize eps
    }
    __syncthreads();

#pragma unroll
    for (int mi = 0; mi < 2; ++mi)
#pragma unroll
        for (int r = 0; r < 4; ++r) {
            int m = mi * 16 + q * 4 + r;
            int n = nb + ln;
            out[(rowBase + m) * 128 + n] = zv[mi][r] * s_inv[m];
        }
}

// ---------------------------------------------------------------- launch ----
extern "C" void kernel_launch(void* const* d_in, const int* in_sizes, int n_in,
                              void* d_out, int out_size, void* d_ws, size_t ws_size,
                              hipStream_t stream) {
    const float* x   = (const float*)d_in[0];   // [8192,128]
    const float* adj = (const float*)d_in[1];   // [8192,8192]
    const float* W   = (const float*)d_in[2];   // [128,128]
    const float* b   = (const float*)d_in[3];   // [128]
    float* out = (float*)d_out;

    unsigned short* yT  = (unsigned short*)d_ws;                         // 2 MB
    float*          dv  = (float*)((char*)d_ws + (2u << 20));            // 32 KB
    unsigned short* Wb  = (unsigned short*)((char*)d_ws + (2u << 20) + 32768);

    gcn_prep<<<256 + 32, 512, 0, stream>>>(adj, x, W, yT, dv, Wb);
    gcn_main<<<256, 512, 0, stream>>>(adj, x, b, yT, dv, Wb, out);
}